// Round 1
// baseline (197.506 us; speedup 1.0000x reference)
//
#include <hip/hip_runtime.h>
#include <math.h>

#define N_RES 4096
#define KNB 32
#define BN_TOTAL 65536  // B*N = 16*4096

// One cyclic-Jacobi rotation zeroing S[p][q]; updates S (two-sided) and V (right).
// Template params keep all array indices compile-time constant (no scratch spills).
template <int p, int q>
__device__ __forceinline__ void jacobi_rot(float S[3][3], float V[3][3]) {
    float apq = S[p][q];
    if (fabsf(apq) > 1e-20f) {
        float app = S[p][p], aqq = S[q][q];
        float tau = (aqq - app) / (2.0f * apq);
        float tt = (tau >= 0.0f ? 1.0f : -1.0f) / (fabsf(tau) + sqrtf(1.0f + tau * tau));
        float c = 1.0f / sqrtf(1.0f + tt * tt);
        float s = tt * c;
#pragma unroll
        for (int i = 0; i < 3; i++) {  // S <- S*G
            float Sip = S[i][p], Siq = S[i][q];
            S[i][p] = c * Sip - s * Siq;
            S[i][q] = s * Sip + c * Siq;
        }
#pragma unroll
        for (int i = 0; i < 3; i++) {  // S <- G^T*S
            float Spi = S[p][i], Sqi = S[q][i];
            S[p][i] = c * Spi - s * Sqi;
            S[q][i] = s * Spi + c * Sqi;
        }
#pragma unroll
        for (int i = 0; i < 3; i++) {  // V <- V*G
            float Vip = V[i][p], Viq = V[i][q];
            V[i][p] = c * Vip - s * Viq;
            V[i][q] = s * Vip + c * Viq;
        }
    }
}

template <int A, int Bc>
__device__ __forceinline__ void sort_pair(float lam[3], float V[3][3]) {
    if (lam[A] < lam[Bc]) {
        float tl = lam[A]; lam[A] = lam[Bc]; lam[Bc] = tl;
#pragma unroll
        for (int i = 0; i < 3; i++) {
            float tv = V[i][A]; V[i][A] = V[i][Bc]; V[i][Bc] = tv;
        }
    }
}

__global__ __launch_bounds__(256) void backbone_kernel(
    const float* __restrict__ frames_rot,   // [B,N,9]
    const float* __restrict__ frames_trans, // [B,N,3]
    const float* __restrict__ pair_rot,     // [B,N,K,9]
    const float* __restrict__ pair_trans,   // [B,N,K,3]
    const float* __restrict__ conf,         // [B,N,K]
    const int* __restrict__ topo,           // [B,N,K]
    float* __restrict__ out)                // [B,N,12]
{
    int g = blockIdx.x * 256 + threadIdx.x;
    int elem = g >> 2;      // (b,n) element index
    int t = g & 3;          // 4 lanes per element, 8 neighbors each
    if (elem >= BN_TOTAL) return;
    int b = elem >> 12;     // N = 4096

    const float* fr_b = frames_rot + (size_t)b * N_RES * 9;
    const float* ft_b = frames_trans + (size_t)b * N_RES * 3;

    size_t kbase = (size_t)elem * KNB + (size_t)t * 8;  // first neighbor index (flat)
    const float4* pr4 = (const float4*)(pair_rot + kbase * 9);  // 288B chunk, 16B aligned
    const float4* pt4 = (const float4*)(pair_trans + kbase * 3);
    const float4* cf4 = (const float4*)(conf + kbase);
    const int4* tp4 = (const int4*)(topo + kbase);

    float Macc[9] = {0, 0, 0, 0, 0, 0, 0, 0, 0};
    float tacc[3] = {0, 0, 0};
    float wsum = 0.0f;

#pragma unroll
    for (int c = 0; c < 2; c++) {  // 2 chunks of 4 neighbors
        float prl[36];
#pragma unroll
        for (int i = 0; i < 9; i++) {
            float4 v = pr4[c * 9 + i];
            prl[4 * i + 0] = v.x; prl[4 * i + 1] = v.y;
            prl[4 * i + 2] = v.z; prl[4 * i + 3] = v.w;
        }
        float ptl[12];
#pragma unroll
        for (int i = 0; i < 3; i++) {
            float4 v = pt4[c * 3 + i];
            ptl[4 * i + 0] = v.x; ptl[4 * i + 1] = v.y;
            ptl[4 * i + 2] = v.z; ptl[4 * i + 3] = v.w;
        }
        float4 wv = cf4[c];
        float wl[4] = {wv.x, wv.y, wv.z, wv.w};
        int4 jv = tp4[c];
        int jl[4] = {jv.x, jv.y, jv.z, jv.w};

#pragma unroll
        for (int kk = 0; kk < 4; kk++) {
            int j = jl[kk];
            const float* Rj = fr_b + j * 9;  // gather: L2-resident (192KB per b)
            const float* Tj = ft_b + j * 3;
            float r[9];
#pragma unroll
            for (int i = 0; i < 9; i++) r[i] = Rj[i];
            float tj[3];
#pragma unroll
            for (int i = 0; i < 3; i++) tj[i] = Tj[i];
            float w = wl[kk];
            const float* pr = prl + kk * 9;
            const float* pt = ptl + kk * 3;
#pragma unroll
            for (int i = 0; i < 3; i++) {
#pragma unroll
                for (int l = 0; l < 3; l++) {
                    // comp_rot = Tj_rot @ pair_rot
                    float cij = r[i * 3 + 0] * pr[0 * 3 + l] +
                                r[i * 3 + 1] * pr[1 * 3 + l] +
                                r[i * 3 + 2] * pr[2 * 3 + l];
                    Macc[i * 3 + l] += w * cij;
                }
                // comp_trans = Tj_rot @ pair_trans + Tj_trans
                float ct = r[i * 3 + 0] * pt[0] + r[i * 3 + 1] * pt[1] +
                           r[i * 3 + 2] * pt[2] + tj[i];
                tacc[i] += w * ct;
            }
            wsum += w;
        }
    }

    // Butterfly reduce across the 4 lanes of this element (lanes are consecutive).
#pragma unroll
    for (int i = 0; i < 9; i++) Macc[i] += __shfl_xor(Macc[i], 1);
#pragma unroll
    for (int i = 0; i < 3; i++) tacc[i] += __shfl_xor(tacc[i], 1);
    wsum += __shfl_xor(wsum, 1);
#pragma unroll
    for (int i = 0; i < 9; i++) Macc[i] += __shfl_xor(Macc[i], 2);
#pragma unroll
    for (int i = 0; i < 3; i++) tacc[i] += __shfl_xor(tacc[i], 2);
    wsum += __shfl_xor(wsum, 2);

    // All 4 lanes now hold full sums; all redundantly do the projection (no divergence),
    // only lane t==0 stores.
    float inv_w = 1.0f / fmaxf(wsum, 1e-20f);
    float M[3][3];
#pragma unroll
    for (int i = 0; i < 3; i++)
#pragma unroll
        for (int j = 0; j < 3; j++) M[i][j] = Macc[i * 3 + j] * inv_w;
    float t0 = tacc[0] * inv_w, t1 = tacc[1] * inv_w, t2 = tacc[2] * inv_w;

    // S = M^T M (symmetric)
    float S[3][3];
#pragma unroll
    for (int i = 0; i < 3; i++)
#pragma unroll
        for (int j = 0; j < 3; j++)
            S[i][j] = M[0][i] * M[0][j] + M[1][i] * M[1][j] + M[2][i] * M[2][j];
    float V[3][3] = {{1, 0, 0}, {0, 1, 0}, {0, 0, 1}};

#pragma unroll
    for (int sweep = 0; sweep < 4; sweep++) {
        jacobi_rot<0, 1>(S, V);
        jacobi_rot<0, 2>(S, V);
        jacobi_rot<1, 2>(S, V);
    }

    float lam[3] = {S[0][0], S[1][1], S[2][2]};
    sort_pair<0, 1>(lam, V);
    sort_pair<1, 2>(lam, V);
    sort_pair<0, 1>(lam, V);

    // Force det(V) = +1 (flip third column; sign lands in sigma3, handled by cross product)
    float detV = V[0][0] * (V[1][1] * V[2][2] - V[1][2] * V[2][1]) -
                 V[0][1] * (V[1][0] * V[2][2] - V[1][2] * V[2][0]) +
                 V[0][2] * (V[1][0] * V[2][1] - V[1][1] * V[2][0]);
    if (detV < 0.0f) { V[0][2] = -V[0][2]; V[1][2] = -V[1][2]; V[2][2] = -V[2][2]; }

    // Bm = M * V ; columns are sigma_i * u_i
    float Bm[3][3];
#pragma unroll
    for (int i = 0; i < 3; i++)
#pragma unroll
        for (int j = 0; j < 3; j++)
            Bm[i][j] = M[i][0] * V[0][j] + M[i][1] * V[1][j] + M[i][2] * V[2][j];

    float u0[3] = {Bm[0][0], Bm[1][0], Bm[2][0]};
    float n0 = u0[0] * u0[0] + u0[1] * u0[1] + u0[2] * u0[2];
    float rn0 = 1.0f / sqrtf(fmaxf(n0, 1e-24f));
    u0[0] *= rn0; u0[1] *= rn0; u0[2] *= rn0;

    float b1[3] = {Bm[0][1], Bm[1][1], Bm[2][1]};
    float d01 = u0[0] * b1[0] + u0[1] * b1[1] + u0[2] * b1[2];
    float u1[3] = {b1[0] - d01 * u0[0], b1[1] - d01 * u0[1], b1[2] - d01 * u0[2]};
    float n1 = u1[0] * u1[0] + u1[1] * u1[1] + u1[2] * u1[2];
    float rn1 = 1.0f / sqrtf(fmaxf(n1, 1e-24f));
    u1[0] *= rn1; u1[1] *= rn1; u1[2] *= rn1;

    // u2 = u0 x u1  (forces det(U)=+1; sigma3 sign absorbed)
    float u2[3] = {u0[1] * u1[2] - u0[2] * u1[1],
                   u0[2] * u1[0] - u0[0] * u1[2],
                   u0[0] * u1[1] - u0[1] * u1[0]};

    // R = U * V^T  == rot_inv of the reference
    float R[9];
#pragma unroll
    for (int i = 0; i < 3; i++) {
        float Ui0 = (i == 0 ? u0[0] : (i == 1 ? u0[1] : u0[2]));
        float Ui1 = (i == 0 ? u1[0] : (i == 1 ? u1[1] : u1[2]));
        float Ui2 = (i == 0 ? u2[0] : (i == 1 ? u2[1] : u2[2]));
#pragma unroll
        for (int j = 0; j < 3; j++)
            R[i * 3 + j] = Ui0 * V[j][0] + Ui1 * V[j][1] + Ui2 * V[j][2];
    }

    if (t == 0) {
        float4* o4 = (float4*)(out + (size_t)elem * 12);
        o4[0] = make_float4(R[0], R[1], R[2], R[3]);
        o4[1] = make_float4(R[4], R[5], R[6], R[7]);
        o4[2] = make_float4(R[8], t0, t1, t2);
    }
}

extern "C" void kernel_launch(void* const* d_in, const int* in_sizes, int n_in,
                              void* d_out, int out_size, void* d_ws, size_t ws_size,
                              hipStream_t stream) {
    const float* frames_rot = (const float*)d_in[0];
    const float* frames_trans = (const float*)d_in[1];
    const float* pair_rot = (const float*)d_in[2];
    const float* pair_trans = (const float*)d_in[3];
    const float* conf = (const float*)d_in[4];
    const int* topo = (const int*)d_in[5];
    float* out = (float*)d_out;

    // BN_TOTAL elements * 4 lanes / 256 threads = 1024 blocks
    dim3 grid(BN_TOTAL * 4 / 256), block(256);
    hipLaunchKernelGGL(backbone_kernel, grid, block, 0, stream,
                       frames_rot, frames_trans, pair_rot, pair_trans, conf, topo, out);
}